// Round 6
// baseline (222.819 us; speedup 1.0000x reference)
//
#include <hip/hip_runtime.h>

#define F_DIM 128
#define C_DIM 100000
#define B_ROWS 512
#define ANGLE 0.5f
#define CPB 128            // classes per arc_main block
#define NCB 782            // ceil(100000/128); 96 OOB pad classes at the end
#define CPAD 100096        // NCB*128, padded class count in w_t
#define OOB_PAD 96.0f      // pad classes contribute exp(0)=1 each to row sums

typedef __attribute__((ext_vector_type(4))) float  f32x4;
typedef __attribute__((ext_vector_type(8))) short  bf16x8;

static __device__ __forceinline__ short f2bf(float x) {
    unsigned int u = __float_as_uint(x);
    u += 0x7FFFu + ((u >> 16) & 1u);      // RNE
    return (short)(u >> 16);
}
static __device__ __forceinline__ float bf2f(unsigned short u) {
    return __uint_as_float((unsigned int)u << 16);
}

// ---------------------------------------------------------------------------
// arc_tr: w [k][c] fp32  ->  w_t [c][k] bf16.  Block = 64 classes x all 128 k.
//   Reads: per inst, 64 lanes span 64 consecutive c at fixed k -> 256B coalesced.
//   Writes: each thread owns a full 64B line of one c-row -> 100% efficiency.
//   Pure streaming, no LDS. c >= C_DIM rows are zero-filled (exp(0)=1, padded).
// ---------------------------------------------------------------------------
__global__ __launch_bounds__(256)
void arc_tr(const float* __restrict__ w, unsigned short* __restrict__ w_t)
{
    const int tid = threadIdx.x;
    const int cl  = tid & 63;
    const int kh  = tid >> 6;              // 0..3 -> k = kh*32 .. +31
    const int c   = blockIdx.x * 64 + cl;

    bf16x8 h[4];
    if (c < C_DIM) {
        #pragma unroll
        for (int q = 0; q < 4; ++q)
            #pragma unroll
            for (int i = 0; i < 8; ++i)
                h[q][i] = f2bf(w[(size_t)(kh * 32 + q * 8 + i) * C_DIM + c]);
    } else {
        #pragma unroll
        for (int q = 0; q < 4; ++q)
            h[q] = (bf16x8){0, 0, 0, 0, 0, 0, 0, 0};
    }
    #pragma unroll
    for (int q = 0; q < 4; ++q)
        *(bf16x8*)&w_t[(size_t)c * 128 + kh * 32 + q * 8] = h[q];
}

// ---------------------------------------------------------------------------
// arc_main: block = 8 waves = 128 classes x 256 batch rows, grid (782, 2).
//   NO LDS, NO barrier. A-fragments load directly from w_t (one b128 each,
//   16 full lines/inst). B-operand = feat fragments in registers. Waves are
//   free-running load->MFMA->exp pipelines.
// ---------------------------------------------------------------------------
__global__ __launch_bounds__(512, 4)
void arc_main(const float* __restrict__ feat,
              const unsigned short* __restrict__ w_t,
              float* __restrict__ pp)        // [NCB][512]
{
    const int tid  = threadIdx.x;
    const int c0   = blockIdx.x * CPB;
    const int r0   = blockIdx.y * 256;
    const int lane = tid & 63;
    const int wv   = tid >> 6;               // 0..7 -> 32-batch strip
    const int quad = lane >> 4;
    const int l15  = lane & 15;

    // ---- feat fragments (B-operand layout), loaded once ----
    bf16x8 fB[2][4];
    #pragma unroll
    for (int s = 0; s < 2; ++s) {
        const int b = r0 + wv * 32 + s * 16 + l15;
        #pragma unroll
        for (int ks = 0; ks < 4; ++ks) {
            const int k0 = ks * 32 + quad * 8;
            const f32x4 u0 = *(const f32x4*)(feat + b * F_DIM + k0);
            const f32x4 u1 = *(const f32x4*)(feat + b * F_DIM + k0 + 4);
            bf16x8 h;
            h[0] = f2bf(u0[0]); h[1] = f2bf(u0[1]); h[2] = f2bf(u0[2]); h[3] = f2bf(u0[3]);
            h[4] = f2bf(u1[0]); h[5] = f2bf(u1[1]); h[6] = f2bf(u1[2]); h[7] = f2bf(u1[3]);
            fB[s][ks] = h;
        }
    }

    // ---- MFMA + exp: A-frags straight from global (L2/L3-resident) ----
    float eA0 = 0.f, eA1 = 0.f, eA2 = 0.f, eA3 = 0.f;
    float eB0 = 0.f, eB1 = 0.f, eB2 = 0.f, eB3 = 0.f;
    #pragma unroll
    for (int m = 0; m < 8; ++m) {
        const unsigned short* wr = w_t + (size_t)(c0 + m * 16 + l15) * 128 + quad * 8;
        f32x4 a0 = {0.f, 0.f, 0.f, 0.f};
        f32x4 a1 = {0.f, 0.f, 0.f, 0.f};
        #pragma unroll
        for (int ks = 0; ks < 4; ++ks) {
            const bf16x8 af = *(const bf16x8*)(wr + ks * 32);
            a0 = __builtin_amdgcn_mfma_f32_16x16x32_bf16(af, fB[0][ks], a0, 0, 0, 0);
            a1 = __builtin_amdgcn_mfma_f32_16x16x32_bf16(af, fB[1][ks], a1, 0, 0, 0);
        }
        eA0 += __expf(a0[0]); eA1 += __expf(a0[1]);
        eA2 += __expf(a0[2]); eA3 += __expf(a0[3]);
        eB0 += __expf(a1[0]); eB1 += __expf(a1[1]);
        eB2 += __expf(a1[2]); eB3 += __expf(a1[3]);
    }

    float esum0 = (eA0 + eA1) + (eA2 + eA3);
    float esum1 = (eB0 + eB1) + (eB2 + eB3);
    esum0 += __shfl_xor(esum0, 16); esum0 += __shfl_xor(esum0, 32);
    esum1 += __shfl_xor(esum1, 16); esum1 += __shfl_xor(esum1, 32);
    if (lane < 16) {
        pp[(size_t)blockIdx.x * 512 + r0 + wv * 32 + lane]      = esum0;
        pp[(size_t)blockIdx.x * 512 + r0 + wv * 32 + 16 + lane] = esum1;
    }
}

// ---------------------------------------------------------------------------
// arc_row: 8 blocks x 256 threads; block handles 64 rows.
//   Phase A: coalesced pp sweep (4-way j split per row).
//   Phase B: target dot from w_t (256B contiguous per row) + norms, 4-way k split.
//   Phase C: margin math per row; Phase D: block partial of the loss sum.
// ---------------------------------------------------------------------------
__global__ __launch_bounds__(256)
void arc_row(const float* __restrict__ feat,
             const unsigned short* __restrict__ w_t,
             const int* __restrict__ target,
             const float* __restrict__ pp,
             float* __restrict__ pl)        // [8] block partials
{
    __shared__ float sPP[4][64];
    __shared__ float sDot[4][64];
    __shared__ float sFsq[4][64];
    __shared__ float sWsq[4][64];
    __shared__ float sT[64];

    const int tid = threadIdx.x;
    const int bl  = tid & 63;                 // row within block
    const int gr  = tid >> 6;                 // 0..3 chunk
    const int b   = blockIdx.x * 64 + bl;

    // Phase A: pp sweep, coalesced (lanes span consecutive b)
    float acc = 0.f;
    for (int j = gr; j < NCB; j += 4)
        acc += pp[(size_t)j * 512 + b];
    sPP[gr][bl] = acc;

    // Phase B: target-column dot + norms, k chunk gr*32..+31
    const int tg = target[b];
    const unsigned short* wr = w_t + (size_t)tg * 128 + gr * 32;
    const float*          fr = feat + b * F_DIM + gr * 32;
    float dot = 0.f, fsq = 0.f, wsq = 0.f;
    #pragma unroll
    for (int i = 0; i < 4; ++i) {
        const bf16x8 hw = *(const bf16x8*)(wr + i * 8);
        const f32x4  f0 = *(const f32x4*)(fr + i * 8);
        const f32x4  f1 = *(const f32x4*)(fr + i * 8 + 4);
        #pragma unroll
        for (int j = 0; j < 4; ++j) {
            const float wv0 = bf2f((unsigned short)hw[j]);
            const float wv1 = bf2f((unsigned short)hw[j + 4]);
            dot += f0[j] * wv0 + f1[j] * wv1;
            wsq += wv0 * wv0 + wv1 * wv1;
            fsq += f0[j] * f0[j] + f1[j] * f1[j];
        }
    }
    sDot[gr][bl] = dot; sFsq[gr][bl] = fsq; sWsq[gr][bl] = wsq;
    __syncthreads();

    // Phase C: per-row margin math (threads 0..63)
    if (tid < 64) {
        const int r = tid;
        const float d  = sDot[0][r] + sDot[1][r] + sDot[2][r] + sDot[3][r];
        const float fq = sFsq[0][r] + sFsq[1][r] + sFsq[2][r] + sFsq[3][r];
        const float wq = sWsq[0][r] + sWsq[1][r] + sWsq[2][r] + sWsq[3][r];
        const float rs = sPP[0][r] + sPP[1][r] + sPP[2][r] + sPP[3][r] - OOB_PAD;
        const float mod = sqrtf(fq) * sqrtf(wq);
        float ct = d / (mod * 1.01f);
        ct = fminf(1.f, fmaxf(-1.f, ct));
        const float th   = acosf(ct) + ANGLE;
        const float marg = mod * cosf(th);
        const float down = rs - expf(d) + expf(marg);
        sT[r] = marg - logf(down);
    }
    __syncthreads();

    // Phase D: reduce 64 terms -> block partial
    if (tid < 32) sT[tid] += sT[tid + 32];
    __syncthreads();
    if (tid < 64) {
        float v = (tid < 32) ? sT[tid] : 0.f;
        #pragma unroll
        for (int off = 16; off > 0; off >>= 1)
            v += __shfl_xor(v, off);
        if (tid == 0) pl[blockIdx.x] = v;
    }
}

// ---------------------------------------------------------------------------
__global__ void arc_loss(const float* __restrict__ pl, float* __restrict__ out)
{
    float v = (threadIdx.x < 8) ? pl[threadIdx.x] : 0.f;
    v += __shfl_xor(v, 1); v += __shfl_xor(v, 2); v += __shfl_xor(v, 4);
    if (threadIdx.x == 0) out[0] = -v / (float)B_ROWS;
}

// ---------------------------------------------------------------------------
extern "C" void kernel_launch(void* const* d_in, const int* in_sizes, int n_in,
                              void* d_out, int out_size, void* d_ws, size_t ws_size,
                              hipStream_t stream)
{
    const float* feat   = (const float*)d_in[0];   // [512,128] fp32
    const float* w      = (const float*)d_in[1];   // [128,100000] fp32
    const int*   target = (const int*)d_in[2];     // [512]

    unsigned short* w_t = (unsigned short*)d_ws;            // [100096][128] bf16
    float* pp = (float*)(w_t + (size_t)CPAD * 128);         // [782][512]
    float* pl = pp + (size_t)NCB * 512;                     // [8]

    arc_tr  <<<CPAD / 64, 256, 0, stream>>>(w, w_t);
    arc_main<<<dim3(NCB, 2), 512, 0, stream>>>(feat, w_t, pp);
    arc_row <<<8, 256, 0, stream>>>(feat, w_t, target, pp, pl);
    arc_loss<<<1, 64, 0, stream>>>(pl, (float*)d_out);
}

// Round 7
// 188.571 us; speedup vs baseline: 1.1816x; 1.1816x over previous
//
#include <hip/hip_runtime.h>
#include <hip/hip_bf16.h>

#define F_DIM 128
#define C_DIM 100000
#define B_ROWS 512
#define ANGLE 0.5f
#define CPB 128            // classes per block
#define NCB 782            // ceil(100000/128); last block has 96 OOB pad classes
#define OOB_PAD 96.0f      // pad classes contribute exp(0)=1 each to row sums

typedef __attribute__((ext_vector_type(4))) float  f32x4;
typedef __attribute__((ext_vector_type(8))) short  bf16x8;

// packed f32x2 -> bf16x2 (v_cvt_pk_bf16_f32 on gfx950); low = a, high = b
static __device__ __forceinline__ unsigned int pk2(float a, float b) {
    __hip_bfloat162 h = __float22bfloat162_rn(float2{a, b});
    return *(unsigned int*)&h;
}

// ---------------------------------------------------------------------------
// arc_main: block = 8 waves = 128 classes x 256 batch rows. grid (782, 2).
//   Phase 1: stage w^T tile (bf16, 16B-chunk XOR swizzle -> conflict-free
//            b128 writes AND reads) using packed cvt. HBM stream issues first.
//   Phase 2: feat fragments in registers (L2-hot, packed cvt).
//   Phase 3: m-loop ds_read_b128 -> MFMA -> exp, 8 parallel accumulators.
//   4 blocks/CU resident (LDS 32KB, VGPR<=64) -> cross-block overlap hides
//   staging barriers.
// ---------------------------------------------------------------------------
__global__ __launch_bounds__(512, 8)
void arc_main(const float* __restrict__ feat,
              const float* __restrict__ w,
              float* __restrict__ pp)        // [NCB][512]
{
    __shared__ unsigned short lBt[128 * 128];   // [c][k] swizzled, 32 KB

    const int tid = threadIdx.x;
    const int c0  = blockIdx.x * CPB;
    const int r0  = blockIdx.y * 256;

    // ---- Phase 1: stage w^T. thread (c, g) covers k = g*32 .. g*32+31 ----
    {
        const int c  = tid & 127;
        const int g  = tid >> 7;              // 0..3
        const int gc = c0 + c;
        #pragma unroll
        for (int j = 0; j < 4; ++j) {
            float v[8];
            #pragma unroll
            for (int i = 0; i < 8; ++i) {
                const int k = g * 32 + j * 8 + i;
                v[i] = (gc < C_DIM) ? w[(size_t)k * C_DIM + gc] : 0.f;
            }
            union { bf16x8 h; unsigned int u[4]; } fr;
            fr.u[0] = pk2(v[0], v[1]); fr.u[1] = pk2(v[2], v[3]);
            fr.u[2] = pk2(v[4], v[5]); fr.u[3] = pk2(v[6], v[7]);
            const int pc = (g * 4 + j) ^ (c & 15);   // 16B-chunk XOR swizzle
            *(bf16x8*)&lBt[c * 128 + pc * 8] = fr.h;
        }
    }
    __syncthreads();

    const int lane = tid & 63;
    const int wv   = tid >> 6;                // 0..7 -> 32-batch strip
    const int quad = lane >> 4;
    const int l15  = lane & 15;

    // ---- Phase 2: feat fragments (B-operand layout), packed cvt ----
    // fB[s][ks] = f[b][k0..k0+7], b = r0+wv*32+s*16+l15, k0 = ks*32+quad*8
    bf16x8 fB[2][4];
    #pragma unroll
    for (int s = 0; s < 2; ++s) {
        const int b = r0 + wv * 32 + s * 16 + l15;
        #pragma unroll
        for (int ks = 0; ks < 4; ++ks) {
            const int k0 = ks * 32 + quad * 8;
            const f32x4 u0 = *(const f32x4*)(feat + b * F_DIM + k0);
            const f32x4 u1 = *(const f32x4*)(feat + b * F_DIM + k0 + 4);
            union { bf16x8 h; unsigned int u[4]; } fr;
            fr.u[0] = pk2(u0[0], u0[1]); fr.u[1] = pk2(u0[2], u0[3]);
            fr.u[2] = pk2(u1[0], u1[1]); fr.u[3] = pk2(u1[2], u1[3]);
            fB[s][ks] = fr.h;
        }
    }

    // ---- Phase 3: MFMA + exp, 8 parallel accumulators ----
    float eA0 = 0.f, eA1 = 0.f, eA2 = 0.f, eA3 = 0.f;
    float eB0 = 0.f, eB1 = 0.f, eB2 = 0.f, eB3 = 0.f;
    #pragma unroll
    for (int m = 0; m < 8; ++m) {
        f32x4 a0 = {0.f, 0.f, 0.f, 0.f};
        f32x4 a1 = {0.f, 0.f, 0.f, 0.f};
        const int row = m * 16 + l15;         // class row
        #pragma unroll
        for (int ks = 0; ks < 4; ++ks) {
            const int pc = (ks * 4 + quad) ^ (row & 15);
            const bf16x8 af = *(const bf16x8*)&lBt[row * 128 + pc * 8];
            a0 = __builtin_amdgcn_mfma_f32_16x16x32_bf16(af, fB[0][ks], a0, 0, 0, 0);
            a1 = __builtin_amdgcn_mfma_f32_16x16x32_bf16(af, fB[1][ks], a1, 0, 0, 0);
        }
        eA0 += __expf(a0[0]); eA1 += __expf(a0[1]);
        eA2 += __expf(a0[2]); eA3 += __expf(a0[3]);
        eB0 += __expf(a1[0]); eB1 += __expf(a1[1]);
        eB2 += __expf(a1[2]); eB3 += __expf(a1[3]);
    }

    float esum0 = (eA0 + eA1) + (eA2 + eA3);
    float esum1 = (eB0 + eB1) + (eB2 + eB3);
    esum0 += __shfl_xor(esum0, 16); esum0 += __shfl_xor(esum0, 32);
    esum1 += __shfl_xor(esum1, 16); esum1 += __shfl_xor(esum1, 32);
    if (lane < 16) {
        pp[(size_t)blockIdx.x * 512 + r0 + wv * 32 + lane]      = esum0;
        pp[(size_t)blockIdx.x * 512 + r0 + wv * 32 + 16 + lane] = esum1;
    }
}

// ---------------------------------------------------------------------------
// arc_row: 8 blocks x 256 threads; block handles 64 rows.
//   Phase A: coalesced pp sweep (lanes span consecutive b; 4-way j split).
//   Phase B: exact fp32 target dot + norms (4-way k split, strided gather).
//   Phase C: per-row margin math; Phase D: block partial of loss sum.
// ---------------------------------------------------------------------------
__global__ __launch_bounds__(256)
void arc_row(const float* __restrict__ feat,
             const float* __restrict__ w,
             const int* __restrict__ target,
             const float* __restrict__ pp,
             float* __restrict__ pl)        // [8] block partials
{
    __shared__ float sPP[4][64];
    __shared__ float sDot[4][64];
    __shared__ float sFsq[4][64];
    __shared__ float sWsq[4][64];
    __shared__ float sT[64];

    const int tid = threadIdx.x;
    const int bl  = tid & 63;                 // row within block
    const int gr  = tid >> 6;                 // 0..3 chunk
    const int b   = blockIdx.x * 64 + bl;

    // Phase A: pp sweep, coalesced
    float acc = 0.f;
    for (int j = gr; j < NCB; j += 4)
        acc += pp[(size_t)j * 512 + b];
    sPP[gr][bl] = acc;

    // Phase B: exact fp32 target-column dot + norms, k chunk gr*32..+31
    const int tg = target[b];
    float dot = 0.f, fsq = 0.f, wsq = 0.f;
    #pragma unroll
    for (int i = 0; i < 32; ++i) {
        const int k = gr * 32 + i;
        const float fv = feat[b * F_DIM + k];
        const float wv = w[(size_t)k * C_DIM + tg];
        dot += fv * wv; fsq += fv * fv; wsq += wv * wv;
    }
    sDot[gr][bl] = dot; sFsq[gr][bl] = fsq; sWsq[gr][bl] = wsq;
    __syncthreads();

    // Phase C: per-row margin math (threads 0..63)
    if (tid < 64) {
        const int r = tid;
        const float d  = sDot[0][r] + sDot[1][r] + sDot[2][r] + sDot[3][r];
        const float fq = sFsq[0][r] + sFsq[1][r] + sFsq[2][r] + sFsq[3][r];
        const float wq = sWsq[0][r] + sWsq[1][r] + sWsq[2][r] + sWsq[3][r];
        const float rs = sPP[0][r] + sPP[1][r] + sPP[2][r] + sPP[3][r] - OOB_PAD;
        const float mod = sqrtf(fq) * sqrtf(wq);
        float ct = d / (mod * 1.01f);
        ct = fminf(1.f, fmaxf(-1.f, ct));
        const float th   = acosf(ct) + ANGLE;
        const float marg = mod * cosf(th);
        const float down = rs - expf(d) + expf(marg);
        sT[r] = marg - logf(down);
    }
    __syncthreads();

    // Phase D: reduce 64 terms -> block partial
    if (tid < 32) sT[tid] += sT[tid + 32];
    __syncthreads();
    if (tid < 64) {
        float v = (tid < 32) ? sT[tid] : 0.f;
        #pragma unroll
        for (int off = 16; off > 0; off >>= 1)
            v += __shfl_xor(v, off);
        if (tid == 0) pl[blockIdx.x] = v;
    }
}

// ---------------------------------------------------------------------------
__global__ void arc_loss(const float* __restrict__ pl, float* __restrict__ out)
{
    float v = (threadIdx.x < 8) ? pl[threadIdx.x] : 0.f;
    v += __shfl_xor(v, 1); v += __shfl_xor(v, 2); v += __shfl_xor(v, 4);
    if (threadIdx.x == 0) out[0] = -v / (float)B_ROWS;
}

// ---------------------------------------------------------------------------
extern "C" void kernel_launch(void* const* d_in, const int* in_sizes, int n_in,
                              void* d_out, int out_size, void* d_ws, size_t ws_size,
                              hipStream_t stream)
{
    const float* feat   = (const float*)d_in[0];   // [512,128] fp32
    const float* w      = (const float*)d_in[1];   // [128,100000] fp32
    const int*   target = (const int*)d_in[2];     // [512]

    float* pp = (float*)d_ws;                      // [782][512], fully overwritten
    float* pl = pp + (size_t)NCB * 512;            // [8]

    arc_main<<<dim3(NCB, 2), 512, 0, stream>>>(feat, w, pp);
    arc_row <<<8, 256, 0, stream>>>(feat, w, target, pp, pl);
    arc_loss<<<1, 64, 0, stream>>>(pl, (float*)d_out);
}

// Round 8
// 166.516 us; speedup vs baseline: 1.3381x; 1.1324x over previous
//
#include <hip/hip_runtime.h>
#include <hip/hip_bf16.h>

#define F_DIM 128
#define C_DIM 100000
#define B_ROWS 512
#define ANGLE 0.5f
#define CPB 128            // classes per block
#define NCB 782            // ceil(100000/128); last block has 96 OOB pad classes
#define OOB_PAD 96.0f      // pad classes contribute exp2(0)=1 each to row sums

typedef __attribute__((ext_vector_type(4))) float  f32x4;
typedef __attribute__((ext_vector_type(8))) short  bf16x8;

// packed f32x2 -> bf16x2 (v_cvt_pk_bf16_f32 on gfx950); low = a, high = b
static __device__ __forceinline__ unsigned int pk2(float a, float b) {
    __hip_bfloat162 h = __float22bfloat162_rn(float2{a, b});
    return *(unsigned int*)&h;
}

#if __has_builtin(__builtin_amdgcn_exp2f)
#define EXP2(x) __builtin_amdgcn_exp2f(x)
#else
#define EXP2(x) exp2f(x)
#endif

// ---------------------------------------------------------------------------
// arc_prep: feat_bf = bf16(log2e * feat). 65536 elements, 8 per thread.
//   Makes arc_main's fragment loads cvt-free and its exp a single v_exp_f32.
// ---------------------------------------------------------------------------
__global__ __launch_bounds__(256)
void arc_prep(const float* __restrict__ feat, unsigned short* __restrict__ fbf)
{
    const int i = (blockIdx.x * 256 + threadIdx.x) * 8;
    const float s = 1.4426950408889634f;   // log2(e)
    const f32x4 a = *(const f32x4*)(feat + i);
    const f32x4 b = *(const f32x4*)(feat + i + 4);
    union { bf16x8 h; unsigned int u[4]; } fr;
    fr.u[0] = pk2(a[0] * s, a[1] * s);
    fr.u[1] = pk2(a[2] * s, a[3] * s);
    fr.u[2] = pk2(b[0] * s, b[1] * s);
    fr.u[3] = pk2(b[2] * s, b[3] * s);
    *(bf16x8*)&fbf[i] = fr.h;
}

// ---------------------------------------------------------------------------
// arc_main: block = 8 waves = 128 classes x 512 batch rows (ALL rows).
//   grid 782 -> w tile staged exactly once grid-wide. Per wave: 32 ds_read_b128
//   A-frags, 128 MFMA, 128 exp2. fB[4][4] fragments direct-loaded from
//   prescaled feat_bf (no cvt). LDS 32 KB, VGPR<=128 -> 2 blocks/CU resident.
// ---------------------------------------------------------------------------
__global__ __launch_bounds__(512, 4)
void arc_main(const unsigned short* __restrict__ fbf,
              const float* __restrict__ w,
              float* __restrict__ pp)        // [NCB][512]
{
    __shared__ unsigned short lBt[128 * 128];   // [c][k] swizzled, 32 KB

    const int tid = threadIdx.x;
    const int cb  = blockIdx.x;
    const int c0  = cb * CPB;

    // ---- Phase 1: stage w^T. thread (c, g) covers k = g*32 .. g*32+31 ----
    {
        const int c  = tid & 127;
        const int g  = tid >> 7;              // 0..3
        const int gc = c0 + c;
        #pragma unroll
        for (int j = 0; j < 4; ++j) {
            float v[8];
            #pragma unroll
            for (int i = 0; i < 8; ++i) {
                const int k = g * 32 + j * 8 + i;
                v[i] = (gc < C_DIM) ? w[(size_t)k * C_DIM + gc] : 0.f;
            }
            union { bf16x8 h; unsigned int u[4]; } fr;
            fr.u[0] = pk2(v[0], v[1]); fr.u[1] = pk2(v[2], v[3]);
            fr.u[2] = pk2(v[4], v[5]); fr.u[3] = pk2(v[6], v[7]);
            const int pc = (g * 4 + j) ^ (c & 15);   // 16B-chunk XOR swizzle
            *(bf16x8*)&lBt[c * 128 + pc * 8] = fr.h;
        }
    }

    const int lane = tid & 63;
    const int wv   = tid >> 6;                // 0..7 -> 64-batch strip
    const int quad = lane >> 4;
    const int l15  = lane & 15;

    // ---- Phase 2: feat fragments, direct bf16 loads (issued pre-barrier) ----
    // fB[s][ks] = fbf[b][k0..k0+7], b = wv*64+s*16+l15, k0 = ks*32+quad*8
    bf16x8 fB[4][4];
    #pragma unroll
    for (int s = 0; s < 4; ++s) {
        const unsigned short* fr = fbf + (size_t)(wv * 64 + s * 16 + l15) * F_DIM + quad * 8;
        #pragma unroll
        for (int ks = 0; ks < 4; ++ks)
            fB[s][ks] = *(const bf16x8*)(fr + ks * 32);
    }
    __syncthreads();

    // ---- Phase 3: m-loop: 4 ds_reads -> 16 MFMA -> 16 exp2 ----
    float esum[4][4];
    #pragma unroll
    for (int s = 0; s < 4; ++s)
        #pragma unroll
        for (int r = 0; r < 4; ++r) esum[s][r] = 0.f;

    #pragma unroll
    for (int m = 0; m < 8; ++m) {
        const int row = m * 16 + l15;         // class row
        f32x4 acc[4];
        #pragma unroll
        for (int s = 0; s < 4; ++s) acc[s] = (f32x4){0.f, 0.f, 0.f, 0.f};
        #pragma unroll
        for (int ks = 0; ks < 4; ++ks) {
            const int pc = (ks * 4 + quad) ^ (row & 15);
            const bf16x8 af = *(const bf16x8*)&lBt[row * 128 + pc * 8];
            #pragma unroll
            for (int s = 0; s < 4; ++s)
                acc[s] = __builtin_amdgcn_mfma_f32_16x16x32_bf16(af, fB[s][ks], acc[s], 0, 0, 0);
        }
        #pragma unroll
        for (int s = 0; s < 4; ++s) {
            esum[s][0] += EXP2(acc[s][0]); esum[s][1] += EXP2(acc[s][1]);
            esum[s][2] += EXP2(acc[s][2]); esum[s][3] += EXP2(acc[s][3]);
        }
    }

    // ---- reduce across quads (same batch col), store pp[cb][batch] ----
    #pragma unroll
    for (int s = 0; s < 4; ++s) {
        float e = (esum[s][0] + esum[s][1]) + (esum[s][2] + esum[s][3]);
        e += __shfl_xor(e, 16); e += __shfl_xor(e, 32);
        if (lane < 16)
            pp[(size_t)cb * 512 + wv * 64 + s * 16 + lane] = e;
    }
}

// ---------------------------------------------------------------------------
// arc_row: exact fp32 target-column terms + partial reduce. One wave per row.
//   512 independent blocks -> latency of the scattered w gather is hidden.
// ---------------------------------------------------------------------------
__global__ void arc_row(const float* __restrict__ feat,
                        const float* __restrict__ w,
                        const int*   __restrict__ target,
                        const float* __restrict__ pp,
                        float* __restrict__ term)
{
    const int b    = blockIdx.x;
    const int lane = threadIdx.x;             // 64
    const int t    = target[b];

    float dot = 0.f, wsq = 0.f, fsq = 0.f, rs = 0.f;
    #pragma unroll
    for (int h = 0; h < 2; ++h) {
        const int f  = lane + h * 64;
        const float fv = feat[b * F_DIM + f];
        const float wv = w[(size_t)f * C_DIM + t];
        dot += fv * wv;
        wsq += wv * wv;
        fsq += fv * fv;
    }
    for (int j = lane; j < NCB; j += 64)
        rs += pp[(size_t)j * 512 + b];

    #pragma unroll
    for (int off = 32; off > 0; off >>= 1) {
        dot += __shfl_xor(dot, off);
        wsq += __shfl_xor(wsq, off);
        fsq += __shfl_xor(fsq, off);
        rs  += __shfl_xor(rs,  off);
    }
    if (lane == 0) {
        const float mod = sqrtf(fsq) * sqrtf(wsq);
        float ct = dot / (mod * 1.01f);
        ct = fminf(1.f, fmaxf(-1.f, ct));
        const float th   = acosf(ct) + ANGLE;
        const float marg = mod * cosf(th);
        const float down = rs - OOB_PAD - expf(dot) + expf(marg);
        term[b] = marg - logf(down);
    }
}

// ---------------------------------------------------------------------------
__global__ void arc_loss(const float* __restrict__ term,
                         float* __restrict__ out)
{
    __shared__ float red[B_ROWS];
    const int b = threadIdx.x;
    red[b] = term[b];
    __syncthreads();
    #pragma unroll
    for (int st = 256; st > 0; st >>= 1) {
        if (b < st) red[b] += red[b + st];
        __syncthreads();
    }
    if (b == 0) out[0] = -red[0] / (float)B_ROWS;
}

// ---------------------------------------------------------------------------
extern "C" void kernel_launch(void* const* d_in, const int* in_sizes, int n_in,
                              void* d_out, int out_size, void* d_ws, size_t ws_size,
                              hipStream_t stream)
{
    const float* feat   = (const float*)d_in[0];   // [512,128] fp32
    const float* w      = (const float*)d_in[1];   // [128,100000] fp32
    const int*   target = (const int*)d_in[2];     // [512]

    unsigned short* fbf = (unsigned short*)d_ws;          // [512][128] bf16, prescaled
    float* pp   = (float*)(fbf + (size_t)B_ROWS * F_DIM); // [782][512]
    float* term = pp + (size_t)NCB * 512;                 // [512]

    arc_prep<<<32, 256, 0, stream>>>(feat, fbf);
    arc_main<<<NCB, 512, 0, stream>>>(fbf, w, pp);
    arc_row <<<B_ROWS, 64, 0, stream>>>(feat, w, target, pp, term);
    arc_loss<<<1, B_ROWS, 0, stream>>>(term, (float*)d_out);
}